// Round 8
// baseline (155.096 us; speedup 1.0000x reference)
//
#include <hip/hip_runtime.h>
#include <hip/hip_bf16.h>

#define B_  8
#define T_  16
#define N_  1024
#define FI  32
#define FO  64
#define K_  3

typedef float  f32x4  __attribute__((ext_vector_type(4)));
typedef short  bf16x8 __attribute__((ext_vector_type(8)));
typedef unsigned short u16x8 __attribute__((ext_vector_type(8)));
typedef unsigned int   u32x4 __attribute__((ext_vector_type(4)));

__device__ inline unsigned short f2bf(float f) {
    unsigned int u = __float_as_uint(f);
    u += 0x7fffu + ((u >> 16) & 1u);
    return (unsigned short)(u >> 16);
}

// packed fp32x2 -> bf16x2 (v_cvt_pk_bf16_f32 on gfx950)
__device__ inline unsigned int pkbf2(float a, float b) {
    __hip_bfloat162 h = __float22bfloat162_rn(make_float2(a, b));
    union { __hip_bfloat162 h2; unsigned int u; } cvt;
    cvt.h2 = h;
    return cvt.u;
}

// async 16-B global -> LDS (global_load_lds_dwordx4); LDS dest is
// wave-uniform base + lane*16 (contiguous per wave).
__device__ inline void gl_lds16(const unsigned short* g, unsigned short* l) {
    __builtin_amdgcn_global_load_lds(
        (const __attribute__((address_space(1))) unsigned int*)g,
        (__attribute__((address_space(3))) unsigned int*)l, 16, 0, 0);
}

// ---------------------------------------------------------------------------
// Kernel 1 "prep": task-split block-uniform branch.
//   tasks 0..2047   : transpose x[b,t,j,f] fp32 -> xt[b, t*32+f, j] bf16
//   tasks 2048..6143: AC[b,k,ij] = cheb[k,ij]*att[b,ij] bf16 (b-parallel)
// ---------------------------------------------------------------------------
__global__ __launch_bounds__(256)
void prep(const float* __restrict__ x, const float* __restrict__ att,
          const float* __restrict__ cheb,
          unsigned short* __restrict__ xt, unsigned short* __restrict__ ac) {
    __shared__ __align__(16) float tile[64][33];
    int task = blockIdx.x;
    int tid  = threadIdx.x;

    if (task < 2048) {
        int jt = task & 15;
        int bt = task >> 4;
        int j0 = jt * 64;
        const float* src = x + (size_t)bt * (N_ * FI) + (size_t)j0 * FI;
        #pragma unroll
        for (int s = 0; s < 2; s++) {
            int e4 = tid + s * 256;
            int j  = e4 >> 3;
            int f4 = e4 & 7;
            f32x4 v = *(const f32x4*)(src + j * FI + f4 * 4);
            tile[j][f4 * 4 + 0] = v[0];
            tile[j][f4 * 4 + 1] = v[1];
            tile[j][f4 * 4 + 2] = v[2];
            tile[j][f4 * 4 + 3] = v[3];
        }
        __syncthreads();
        int f  = tid >> 3;
        int j8 = (tid & 7) * 8;
        u32x4 pk;
        #pragma unroll
        for (int u = 0; u < 4; u++)
            pk[u] = pkbf2(tile[j8 + 2 * u][f], tile[j8 + 2 * u + 1][f]);
        *(u32x4*)(xt + (size_t)bt * (32 * 1024) + j0 + f * 1024 + j8) = pk;
    } else {
        int e  = (task - 2048) * 256 + tid;   // 0..1048575
        int b  = e >> 17;
        size_t ij = (size_t)(e & 131071) * 8;
        const float* ap = att + (size_t)b * (N_ * N_) + ij;
        f32x4 a0 = ((const f32x4*)ap)[0];
        f32x4 a1 = ((const f32x4*)ap)[1];
        #pragma unroll
        for (int k = 0; k < K_; k++) {
            const float* cp = cheb + (size_t)k * (N_ * N_) + ij;
            f32x4 c0 = ((const f32x4*)cp)[0];
            f32x4 c1 = ((const f32x4*)cp)[1];
            u32x4 pk;
            pk[0] = pkbf2(c0[0] * a0[0], c0[1] * a0[1]);
            pk[1] = pkbf2(c0[2] * a0[2], c0[3] * a0[3]);
            pk[2] = pkbf2(c1[0] * a1[0], c1[1] * a1[1]);
            pk[3] = pkbf2(c1[2] * a1[2], c1[3] * a1[3]);
            *(u32x4*)(ac + (size_t)(b * K_ + k) * (N_ * N_) + ij) = pk;
        }
    }
}

// ---------------------------------------------------------------------------
// Kernel 2 v3: rhs[b,t,i,k*32+f] = sum_j AC[b,k,i,j] * xt[b,t*32+f,j]
// 128x128 tile, BK=64 (32 MFMA/wave per barrier-pair, 16 iters),
// XOR-swizzled LDS (16-B granule ^ (row&7)) -> 2-way banks (free).
// lds-DMA staging: lane fetches the swizzled global granule so the
// fixed base+lane*16 DMA lands it at the swizzled LDS slot.
// grid: 768 = 8 XCD * (3 lbk * 32 tiles); XCD owns b=xcd.
// ---------------------------------------------------------------------------
__global__ __launch_bounds__(256)
void stage1_gemm(const unsigned short* __restrict__ ac,
                 const unsigned short* __restrict__ xt,
                 unsigned short* __restrict__ rhs) {
    int blk  = blockIdx.x;
    int xcd  = blk & 7;
    int slot = blk >> 3;          // 0..95
    int lbk  = slot >> 5;         // 0..2
    int tile = slot & 31;
    int bk   = xcd * 3 + lbk;     // 0..23
    int b    = bk / K_;           // == xcd
    int kk   = bk - b * K_;
    int i0   = (tile >> 2) * 128;
    int c0   = (tile & 3) * 128;

    const unsigned short* A  = ac + (size_t)bk * (N_ * N_);
    const unsigned short* Bx = xt + (size_t)b * (512 * 1024);

    __shared__ __align__(16) unsigned short As[128 * 64];  // 16 KB, swizzled
    __shared__ __align__(16) unsigned short Bs[128 * 64];  // 16 KB, swizzled

    int tid  = threadIdx.x;
    int lane = tid & 63;
    int w    = tid >> 6;
    int wrow = (w >> 1) * 64;
    int wcol = (w & 1) * 64;
    int quad = lane >> 4;
    int l15  = lane & 15;

    f32x4 acc[4][4];
    #pragma unroll
    for (int mt = 0; mt < 4; mt++)
        #pragma unroll
        for (int nt = 0; nt < 4; nt++)
            acc[mt][nt] = (f32x4){0.f, 0.f, 0.f, 0.f};

    // staging: thread -> LDS granule tid (16 B); row sr = tid>>3,
    // physical in-row granule g = tid&7 holds logical granule g^(sr&7).
    int sr = tid >> 3;                       // 0..31 (+32 per chunk)
    int sc = ((tid & 7) ^ (sr & 7)) * 8;     // swizzled elem offset in row

    const unsigned short* Ag = A  + (size_t)(i0 + sr) * N_ + sc;
    const unsigned short* Bg = Bx + (size_t)(c0 + sr) * N_ + sc;
    unsigned short* Al = As + tid * 8;
    unsigned short* Bl = Bs + tid * 8;

    for (int kb = 0; kb < 16; kb++) {
        int j0 = kb * 64;
        __syncthreads();
        #pragma unroll
        for (int s = 0; s < 4; s++) {        // rows +0,+32,+64,+96 (swizzle
            gl_lds16(Ag + j0 + (size_t)(s * 32) * N_, Al + s * 32 * 64);  // invariant: 32%8==0)
            gl_lds16(Bg + j0 + (size_t)(s * 32) * N_, Bl + s * 32 * 64);
        }
        __syncthreads();

        #pragma unroll
        for (int ks = 0; ks < 2; ks++) {
            bf16x8 af[4], bfr[4];
            #pragma unroll
            for (int mt = 0; mt < 4; mt++) {
                int R = wrow + mt * 16 + l15;
                int p = (ks * 4 + quad) ^ (R & 7);
                af[mt] = *(const bf16x8*)(As + R * 64 + p * 8);
            }
            #pragma unroll
            for (int nt = 0; nt < 4; nt++) {
                int R = wcol + nt * 16 + l15;
                int p = (ks * 4 + quad) ^ (R & 7);
                bfr[nt] = *(const bf16x8*)(Bs + R * 64 + p * 8);
            }
            #pragma unroll
            for (int mt = 0; mt < 4; mt++)
                #pragma unroll
                for (int nt = 0; nt < 4; nt++)
                    acc[mt][nt] = __builtin_amdgcn_mfma_f32_16x16x32_bf16(
                        af[mt], bfr[nt], acc[mt][nt], 0, 0, 0);
        }
    }

    // epilogue: C/D layout col=lane&15 (c = t*32+f), row=quad*4+reg (i)
    #pragma unroll
    for (int mt = 0; mt < 4; mt++) {
        #pragma unroll
        for (int nt = 0; nt < 4; nt++) {
            int ci = c0 + wcol + nt * 16 + l15;
            int tt = ci >> 5;
            int ff = ci & 31;
            #pragma unroll
            for (int reg = 0; reg < 4; reg++) {
                int ii = i0 + wrow + mt * 16 + quad * 4 + reg;
                rhs[(((size_t)b * T_ + tt) * N_ + ii) * 96 + kk * 32 + ff] =
                    f2bf(acc[mt][nt][reg]);
            }
        }
    }
}

// ---------------------------------------------------------------------------
// Kernel 3: out[row, o] = relu( sum_q rhs_bf16[row, q] * Theta[q, o] )
// ---------------------------------------------------------------------------
#define TS_LD 104
__global__ __launch_bounds__(256)
void stage2_mfma(const unsigned short* __restrict__ rhs,
                 const float* __restrict__ theta, float* __restrict__ out) {
    __shared__ __align__(16) unsigned short As[128 * 96];
    __shared__ __align__(16) unsigned short Ts[64 * TS_LD];

    int tid  = threadIdx.x;
    int lane = tid & 63;
    int w    = tid >> 6;
    int quad = lane >> 4;
    int l15  = lane & 15;
    size_t row0 = (size_t)blockIdx.x * 128;

    #pragma unroll
    for (int s = 0; s < 24; s++) {
        int e = tid + s * 256;
        int q = e >> 6, o = e & 63;
        Ts[o * TS_LD + q] = f2bf(theta[e]);
    }
    {
        const u16x8* g = (const u16x8*)(rhs + row0 * 96);
        u16x8* l = (u16x8*)As;
        #pragma unroll
        for (int s = 0; s < 6; s++)
            l[s * 256 + tid] = g[s * 256 + tid];
    }
    __syncthreads();

    f32x4 acc[2][4];
    #pragma unroll
    for (int mt = 0; mt < 2; mt++)
        #pragma unroll
        for (int nt = 0; nt < 4; nt++)
            acc[mt][nt] = (f32x4){0.f, 0.f, 0.f, 0.f};

    #pragma unroll
    for (int kc = 0; kc < 3; kc++) {
        bf16x8 bfr[4];
        #pragma unroll
        for (int nt = 0; nt < 4; nt++)
            bfr[nt] = *(const bf16x8*)(Ts + (nt * 16 + l15) * TS_LD + kc * 32 + quad * 8);
        #pragma unroll
        for (int mt = 0; mt < 2; mt++) {
            bf16x8 af = *(const bf16x8*)(As + (w * 32 + mt * 16 + l15) * 96 + kc * 32 + quad * 8);
            #pragma unroll
            for (int nt = 0; nt < 4; nt++)
                acc[mt][nt] = __builtin_amdgcn_mfma_f32_16x16x32_bf16(
                    af, bfr[nt], acc[mt][nt], 0, 0, 0);
        }
    }

    #pragma unroll
    for (int mt = 0; mt < 2; mt++) {
        #pragma unroll
        for (int nt = 0; nt < 4; nt++) {
            int o = nt * 16 + l15;
            #pragma unroll
            for (int reg = 0; reg < 4; reg++) {
                size_t row = row0 + w * 32 + mt * 16 + quad * 4 + reg;
                out[row * 64 + o] = fmaxf(acc[mt][nt][reg], 0.f);
            }
        }
    }
}

// ---------------------------------------------------------------------------
extern "C" void kernel_launch(void* const* d_in, const int* in_sizes, int n_in,
                              void* d_out, int out_size, void* d_ws, size_t ws_size,
                              hipStream_t stream) {
    const float* x     = (const float*)d_in[0];   // [B,T,N,FI]
    const float* att   = (const float*)d_in[1];   // [B,N,N]
    const float* cheb  = (const float*)d_in[2];   // [K,N,N]
    const float* theta = (const float*)d_in[3];   // [K,FI,FO]
    float* out = (float*)d_out;                   // [B,T,N,FO]

    // workspace: xt bf16 8.4 MB | rhs bf16 25.2 MB | ac bf16 50.3 MB
    unsigned short* xt  = (unsigned short*)d_ws;
    unsigned short* rhs = xt  + (size_t)B_ * 512 * 1024;
    unsigned short* ac  = rhs + (size_t)B_ * T_ * N_ * 96;

    prep<<<2048 + 4096, 256, 0, stream>>>(x, att, cheb, xt, ac);
    stage1_gemm<<<768, 256, 0, stream>>>(ac, xt, rhs);
    stage2_mfma<<<(B_ * T_ * N_) / 128, 256, 0, stream>>>(rhs, theta, out);
}

// Round 9
// 153.925 us; speedup vs baseline: 1.0076x; 1.0076x over previous
//
#include <hip/hip_runtime.h>
#include <hip/hip_bf16.h>

#define B_  8
#define T_  16
#define N_  1024
#define FI  32
#define FO  64
#define K_  3

typedef float  f32x4  __attribute__((ext_vector_type(4)));
typedef short  bf16x8 __attribute__((ext_vector_type(8)));
typedef unsigned short u16x8 __attribute__((ext_vector_type(8)));
typedef unsigned int   u32x4 __attribute__((ext_vector_type(4)));

__device__ inline unsigned short f2bf(float f) {
    unsigned int u = __float_as_uint(f);
    u += 0x7fffu + ((u >> 16) & 1u);
    return (unsigned short)(u >> 16);
}

// packed fp32x2 -> bf16x2 (v_cvt_pk_bf16_f32 on gfx950)
__device__ inline unsigned int pkbf2(float a, float b) {
    __hip_bfloat162 h = __float22bfloat162_rn(make_float2(a, b));
    union { __hip_bfloat162 h2; unsigned int u; } cvt;
    cvt.h2 = h;
    return cvt.u;
}

// async 16-B global -> LDS (global_load_lds_dwordx4); LDS dest is
// wave-uniform base + lane*16 (contiguous per wave).
__device__ inline void gl_lds16(const unsigned short* g, unsigned short* l) {
    __builtin_amdgcn_global_load_lds(
        (const __attribute__((address_space(1))) unsigned int*)g,
        (__attribute__((address_space(3))) unsigned int*)l, 16, 0, 0);
}

// ---------------------------------------------------------------------------
// Kernel 1 "prep": task-split block-uniform branch.
//   tasks 0..2047   : transpose x[b,t,j,f] fp32 -> xt[b, t*32+f, j] bf16
//   tasks 2048..6143: AC[b,k,ij] = cheb[k,ij]*att[b,ij] bf16 (b-parallel)
// ---------------------------------------------------------------------------
__global__ __launch_bounds__(256)
void prep(const float* __restrict__ x, const float* __restrict__ att,
          const float* __restrict__ cheb,
          unsigned short* __restrict__ xt, unsigned short* __restrict__ ac) {
    __shared__ __align__(16) float tile[64][33];
    int task = blockIdx.x;
    int tid  = threadIdx.x;

    if (task < 2048) {
        int jt = task & 15;
        int bt = task >> 4;
        int j0 = jt * 64;
        const float* src = x + (size_t)bt * (N_ * FI) + (size_t)j0 * FI;
        #pragma unroll
        for (int s = 0; s < 2; s++) {
            int e4 = tid + s * 256;
            int j  = e4 >> 3;
            int f4 = e4 & 7;
            f32x4 v = *(const f32x4*)(src + j * FI + f4 * 4);
            tile[j][f4 * 4 + 0] = v[0];
            tile[j][f4 * 4 + 1] = v[1];
            tile[j][f4 * 4 + 2] = v[2];
            tile[j][f4 * 4 + 3] = v[3];
        }
        __syncthreads();
        int f  = tid >> 3;
        int j8 = (tid & 7) * 8;
        u32x4 pk;
        #pragma unroll
        for (int u = 0; u < 4; u++)
            pk[u] = pkbf2(tile[j8 + 2 * u][f], tile[j8 + 2 * u + 1][f]);
        *(u32x4*)(xt + (size_t)bt * (32 * 1024) + j0 + f * 1024 + j8) = pk;
    } else {
        int e  = (task - 2048) * 256 + tid;   // 0..1048575
        int b  = e >> 17;
        size_t ij = (size_t)(e & 131071) * 8;
        const float* ap = att + (size_t)b * (N_ * N_) + ij;
        f32x4 a0 = ((const f32x4*)ap)[0];
        f32x4 a1 = ((const f32x4*)ap)[1];
        #pragma unroll
        for (int k = 0; k < K_; k++) {
            const float* cp = cheb + (size_t)k * (N_ * N_) + ij;
            f32x4 c0 = ((const f32x4*)cp)[0];
            f32x4 c1 = ((const f32x4*)cp)[1];
            u32x4 pk;
            pk[0] = pkbf2(c0[0] * a0[0], c0[1] * a0[1]);
            pk[1] = pkbf2(c0[2] * a0[2], c0[3] * a0[3]);
            pk[2] = pkbf2(c1[0] * a1[0], c1[1] * a1[1]);
            pk[3] = pkbf2(c1[2] * a1[2], c1[3] * a1[3]);
            *(u32x4*)(ac + (size_t)(b * K_ + k) * (N_ * N_) + ij) = pk;
        }
    }
}

// ---------------------------------------------------------------------------
// Kernel 2: rhs_bf16[b,t,i, k*32+f] = sum_j AC[b,k,i,j] * xt[b, t*32+f, j]
// R3/R7-proven: 128x128 tile, BK=32, global_load_lds x16, XCD swizzle.
// (R8's BK=64 + XOR swizzle was neutral -> reverted; barrier drain is
//  structural to the 2-barrier K-loop, not bank/width-limited.)
// ---------------------------------------------------------------------------
__global__ __launch_bounds__(256)
void stage1_gemm(const unsigned short* __restrict__ ac,
                 const unsigned short* __restrict__ xt,
                 unsigned short* __restrict__ rhs) {
    int blk  = blockIdx.x;
    int xcd  = blk & 7;
    int slot = blk >> 3;          // 0..95
    int lbk  = slot >> 5;         // 0..2
    int tile = slot & 31;
    int bk   = xcd * 3 + lbk;     // 0..23
    int b    = bk / K_;           // == xcd
    int kk   = bk - b * K_;
    int i0   = (tile >> 2) * 128;
    int c0   = (tile & 3) * 128;

    const unsigned short* A  = ac + (size_t)bk * (N_ * N_);
    const unsigned short* Bx = xt + (size_t)b * (512 * 1024);

    __shared__ __align__(16) unsigned short As[128 * 32];  // unpadded: lds-DMA
    __shared__ __align__(16) unsigned short Bs[128 * 32];

    int tid  = threadIdx.x;
    int lane = tid & 63;
    int w    = tid >> 6;
    int wrow = (w >> 1) * 64;
    int wcol = (w & 1) * 64;
    int quad = lane >> 4;
    int l15  = lane & 15;

    f32x4 acc[4][4];
    #pragma unroll
    for (int mt = 0; mt < 4; mt++)
        #pragma unroll
        for (int nt = 0; nt < 4; nt++)
            acc[mt][nt] = (f32x4){0.f, 0.f, 0.f, 0.f};

    int sr = tid >> 2;          // 0..63
    int sc = (tid & 3) * 8;     // 0/8/16/24

    const unsigned short* Ag = A  + (size_t)(i0 + sr) * N_ + sc;
    const unsigned short* Bg = Bx + (size_t)(c0 + sr) * N_ + sc;
    unsigned short* Al = As + tid * 8;
    unsigned short* Bl = Bs + tid * 8;

    for (int kb = 0; kb < 32; kb++) {
        int j0 = kb * 32;
        __syncthreads();
        gl_lds16(Ag + j0,           Al);
        gl_lds16(Ag + j0 + 64 * N_, Al + 64 * 32);
        gl_lds16(Bg + j0,           Bl);
        gl_lds16(Bg + j0 + 64 * N_, Bl + 64 * 32);
        __syncthreads();

        bf16x8 af[4], bfr[4];
        #pragma unroll
        for (int mt = 0; mt < 4; mt++)
            af[mt] = *(const bf16x8*)(As + (wrow + mt * 16 + l15) * 32 + quad * 8);
        #pragma unroll
        for (int nt = 0; nt < 4; nt++)
            bfr[nt] = *(const bf16x8*)(Bs + (wcol + nt * 16 + l15) * 32 + quad * 8);
        #pragma unroll
        for (int mt = 0; mt < 4; mt++)
            #pragma unroll
            for (int nt = 0; nt < 4; nt++)
                acc[mt][nt] = __builtin_amdgcn_mfma_f32_16x16x32_bf16(
                    af[mt], bfr[nt], acc[mt][nt], 0, 0, 0);
    }

    // epilogue: C/D layout col=lane&15 (c = t*32+f), row=quad*4+reg (i)
    #pragma unroll
    for (int mt = 0; mt < 4; mt++) {
        #pragma unroll
        for (int nt = 0; nt < 4; nt++) {
            int ci = c0 + wcol + nt * 16 + l15;
            int tt = ci >> 5;
            int ff = ci & 31;
            #pragma unroll
            for (int reg = 0; reg < 4; reg++) {
                int ii = i0 + wrow + mt * 16 + quad * 4 + reg;
                rhs[(((size_t)b * T_ + tt) * N_ + ii) * 96 + kk * 32 + ff] =
                    f2bf(acc[mt][nt][reg]);
            }
        }
    }
}

// ---------------------------------------------------------------------------
// Kernel 3 v2: out[row, o] = relu( sum_q rhs_bf16[row, q] * Theta[q, o] )
// A-fragments read DIRECTLY from global (each 192-B rhs row consumed exactly
// once, 16 rows x 64 B dense per load instr) — no rhs LDS round-trip.
// Theta^T staged in LDS (B-frags need the transpose). LDS 13.3 KB.
// ---------------------------------------------------------------------------
#define TS_LD 104
__global__ __launch_bounds__(256)
void stage2_mfma(const unsigned short* __restrict__ rhs,
                 const float* __restrict__ theta, float* __restrict__ out) {
    __shared__ __align__(16) unsigned short Ts[64 * TS_LD];

    int tid  = threadIdx.x;
    int lane = tid & 63;
    int w    = tid >> 6;
    int quad = lane >> 4;
    int l15  = lane & 15;
    size_t row0 = (size_t)blockIdx.x * 128;

    #pragma unroll
    for (int s = 0; s < 24; s++) {
        int e = tid + s * 256;
        int q = e >> 6, o = e & 63;
        Ts[o * TS_LD + q] = f2bf(theta[e]);
    }
    __syncthreads();

    f32x4 acc[2][4];
    #pragma unroll
    for (int mt = 0; mt < 2; mt++)
        #pragma unroll
        for (int nt = 0; nt < 4; nt++)
            acc[mt][nt] = (f32x4){0.f, 0.f, 0.f, 0.f};

    #pragma unroll
    for (int kc = 0; kc < 3; kc++) {
        bf16x8 bfr[4];
        #pragma unroll
        for (int nt = 0; nt < 4; nt++)
            bfr[nt] = *(const bf16x8*)(Ts + (nt * 16 + l15) * TS_LD + kc * 32 + quad * 8);
        #pragma unroll
        for (int mt = 0; mt < 2; mt++) {
            bf16x8 af = *(const bf16x8*)(
                rhs + (row0 + w * 32 + mt * 16 + l15) * 96 + kc * 32 + quad * 8);
            #pragma unroll
            for (int nt = 0; nt < 4; nt++)
                acc[mt][nt] = __builtin_amdgcn_mfma_f32_16x16x32_bf16(
                    af, bfr[nt], acc[mt][nt], 0, 0, 0);
        }
    }

    #pragma unroll
    for (int mt = 0; mt < 2; mt++) {
        #pragma unroll
        for (int nt = 0; nt < 4; nt++) {
            int o = nt * 16 + l15;
            #pragma unroll
            for (int reg = 0; reg < 4; reg++) {
                size_t row = row0 + w * 32 + mt * 16 + quad * 4 + reg;
                out[row * 64 + o] = fmaxf(acc[mt][nt][reg], 0.f);
            }
        }
    }
}

// ---------------------------------------------------------------------------
extern "C" void kernel_launch(void* const* d_in, const int* in_sizes, int n_in,
                              void* d_out, int out_size, void* d_ws, size_t ws_size,
                              hipStream_t stream) {
    const float* x     = (const float*)d_in[0];   // [B,T,N,FI]
    const float* att   = (const float*)d_in[1];   // [B,N,N]
    const float* cheb  = (const float*)d_in[2];   // [K,N,N]
    const float* theta = (const float*)d_in[3];   // [K,FI,FO]
    float* out = (float*)d_out;                   // [B,T,N,FO]

    // workspace: xt bf16 8.4 MB | rhs bf16 25.2 MB | ac bf16 50.3 MB
    unsigned short* xt  = (unsigned short*)d_ws;
    unsigned short* rhs = xt  + (size_t)B_ * 512 * 1024;
    unsigned short* ac  = rhs + (size_t)B_ * T_ * N_ * 96;

    prep<<<2048 + 4096, 256, 0, stream>>>(x, att, cheb, xt, ac);
    stage1_gemm<<<768, 256, 0, stream>>>(ac, xt, rhs);
    stage2_mfma<<<(B_ * T_ * N_) / 128, 256, 0, stream>>>(rhs, theta, out);
}